// Round 13
// baseline (311.720 us; speedup 1.0000x reference)
//
#include <hip/hip_runtime.h>
#include <hip/hip_bf16.h>
#include <cstdint>
#include <cstddef>

#define N_NODES 10000
#define T_STEPS 6
#define F_IN    64
#define HID     64
#define HEADS   4
#define E_EDGES 160000
#define EP      (E_EDGES + N_NODES)   /* 170000 edges incl self-loops */
#define TN      (T_STEPS * N_NODES)   /* 60000 */
#define NTILES  (TN / 16)             /* 3750 */

typedef __hip_bfloat16 bf16;
typedef __attribute__((ext_vector_type(8))) short short8;
typedef __attribute__((ext_vector_type(4))) float floatx4;

__device__ __forceinline__ float b2f(bf16 v) { return __bfloat162float(v); }
__device__ __forceinline__ float bfu(unsigned short s) { return __uint_as_float((unsigned)s << 16); }
__device__ __forceinline__ unsigned short f2bu(float f) {
    bf16 b = __float2bfloat16(f);
    return *(unsigned short*)&b;
}
__device__ __forceinline__ float sel4(float4 v, int h) {
    float r = v.x;
    r = (h == 1) ? v.y : r;
    r = (h == 2) ? v.z : r;
    r = (h == 3) ? v.w : r;
    return r;
}
__device__ __forceinline__ void lds_fence() {
    asm volatile("s_waitcnt lgkmcnt(0)" ::: "memory");
}

/* ---------------- CSR build ---------------- */

__global__ void k_count(const int* ei, int* counts) {
    int e = blockIdx.x * blockDim.x + threadIdx.x;
    if (e >= EP) return;
    int dst = (e < E_EDGES) ? ei[E_EDGES + e] : (e - E_EDGES);
    atomicAdd(&counts[dst], 1);
}

__global__ void k_scan(const int* counts, int* rowstart) {
    __shared__ int part[1024];
    int tid = threadIdx.x;
    const int chunk = (N_NODES + 1023) / 1024;  // 10
    int base = tid * chunk;
    int s = 0;
    for (int i = 0; i < chunk; i++) { int idx = base + i; if (idx < N_NODES) s += counts[idx]; }
    part[tid] = s;
    __syncthreads();
    for (int off = 1; off < 1024; off <<= 1) {
        int v = (tid >= off) ? part[tid - off] : 0;
        __syncthreads();
        part[tid] += v;
        __syncthreads();
    }
    int run = (tid == 0) ? 0 : part[tid - 1];
    for (int i = 0; i < chunk; i++) {
        int idx = base + i;
        if (idx < N_NODES) { rowstart[idx] = run; run += counts[idx]; }
    }
    if (tid == 0) rowstart[N_NODES] = EP;
}

__global__ void k_scatter(const int* ei, const int* rowstart, int* fill,
                          int* csr_src, int* csr_eid) {
    int e = blockIdx.x * blockDim.x + threadIdx.x;
    if (e >= EP) return;
    int src = (e < E_EDGES) ? ei[e] : (e - E_EDGES);
    int dst = (e < E_EDGES) ? ei[E_EDGES + e] : (e - E_EDGES);
    int pos = rowstart[dst] + atomicAdd(&fill[dst], 1);
    csr_src[pos] = src;
    csr_eid[pos] = e;
}

/* ---------------- prep: P-matrices + transposed bf16 W1 ---------------- */

__global__ __launch_bounds__(256) void k_prep1(const float* __restrict__ W1,
                                               const float* __restrict__ a_src1,
                                               const float* __restrict__ a_dst1,
                                               float* __restrict__ P1s,
                                               float* __restrict__ P1d,
                                               bf16* __restrict__ W1tb) {
    int tid = threadIdx.x;
    int h = tid >> 6, k = tid & 63;
    float ps = 0.f, pd = 0.f;
    for (int c = 0; c < 64; c++) {
        float wv = W1[k * 256 + h * 64 + c];
        ps += wv * a_src1[h * 64 + c];
        pd += wv * a_dst1[h * 64 + c];
    }
    P1s[h * 64 + k] = ps;
    P1d[h * 64 + k] = pd;
    /* W1tb[c][K] = W1[K&63][ (K>>6)*64 + c ]  (Wbig^T, bf16) */
    for (int i = tid; i < 64 * 256; i += 256) {
        int c = i >> 8, K = i & 255;
        W1tb[i] = __float2bfloat16(W1[(K & 63) * 256 + (K >> 6) * 64 + c]);
    }
}

/* ---------------- GAT layer 0 GEMM (MFMA) ---------------- */
__global__ __launch_bounds__(256) void k_gemm0(const float* __restrict__ x,
                                               const float* __restrict__ W0,
                                               const float* __restrict__ a_src0,
                                               const float* __restrict__ a_dst0,
                                               bf16* __restrict__ XW0b,
                                               float* __restrict__ ALS0,
                                               float* __restrict__ ALD0) {
    __shared__ __align__(16) bf16 wt[64 * 64];   /* [c][k], 8 KB */
    int tid = threadIdx.x;
    for (int i = tid; i < 4096; i += 256) {
        int c = i >> 6, k = i & 63;
        wt[i] = __float2bfloat16(W0[k * 64 + c]);
    }
    __syncthreads();
    int wv = tid >> 6, lane = tid & 63;
    int tile = blockIdx.x * 4 + wv;
    if (tile >= NTILES) return;
    int rb = tile * 16;
    int m = lane & 15, quad = lane >> 4;
    int row = rb + m;
    int t = row / N_NODES, n = row - t * N_NODES;
    const float* xr = x + ((size_t)n * T_STEPS + t) * F_IN + quad * 8;
    short8 a0, a1;
#pragma unroll
    for (int j = 0; j < 8; j++) {
        a0[j] = (short)f2bu(xr[j]);
        a1[j] = (short)f2bu(xr[32 + j]);
    }
    floatx4 acc[4];
#pragma unroll
    for (int ct = 0; ct < 4; ct++) {
        short8 bb0 = *(const short8*)(wt + (ct * 16 + m) * 64 + quad * 8);
        short8 bb1 = *(const short8*)(wt + (ct * 16 + m) * 64 + 32 + quad * 8);
        floatx4 a = {0.f, 0.f, 0.f, 0.f};
        a = __builtin_amdgcn_mfma_f32_16x16x32_bf16(a0, bb0, a, 0, 0, 0);
        a = __builtin_amdgcn_mfma_f32_16x16x32_bf16(a1, bb1, a, 0, 0, 0);
        acc[ct] = a;
    }
#pragma unroll
    for (int ct = 0; ct < 4; ct++) {
        float as0 = a_src0[ct * 16 + m], ad0 = a_dst0[ct * 16 + m];
#pragma unroll
        for (int r = 0; r < 4; r++) {
            int orow = rb + quad * 4 + r;
            float v = acc[ct][r];
            XW0b[(size_t)orow * 64 + ct * 16 + m] = __float2bfloat16(v);
            float ps = v * as0, pd = v * ad0;
#pragma unroll
            for (int o = 8; o; o >>= 1) { ps += __shfl_xor(ps, o, 64); pd += __shfl_xor(pd, o, 64); }
            if (m == 0) { ALS0[orow * 4 + ct] = ps; ALD0[orow * 4 + ct] = pd; }
        }
    }
}

/* ---------------- fused layer-0: softmax + accumulate ---------------- */
__global__ __launch_bounds__(256) void k_fused0(const int* __restrict__ rowst,
                                                const int* __restrict__ csr_src,
                                                const bf16* __restrict__ XW0b,
                                                const float* __restrict__ ALS0,
                                                const float* __restrict__ ALD0,
                                                const float* __restrict__ b0,
                                                bf16* __restrict__ H0b) {
    __shared__ float exv[4][256];
    __shared__ int   srcs[4][64];
    int tid = threadIdx.x;
    int wv = tid >> 6;
    int wid = blockIdx.x * 4 + wv;
    int lane = tid & 63;
    int t = wid / N_NODES, n = wid % N_NODES;
    int rs = rowst[n], re = rowst[n + 1];
    int deg = re - rs;
    int tb = t * N_NODES;
    float4 ad = *(const float4*)(ALD0 + (size_t)wid * 4);
    int g = lane >> 4, il = lane & 15;
    int h = il >> 2;
    floatx4 av = {0.f, 0.f, 0.f, 0.f};
    float scale_h;

    if (deg <= 64) {
        int e = rs + lane;
        bool valid = e < re;
        int src = csr_src[valid ? e : rs];
        float4 as = *(const float4*)(ALS0 + (size_t)(tb + src) * 4);
        float l0 = as.x + ad.x; l0 = l0 > 0.f ? l0 : 0.2f * l0; l0 = fminf(l0, 80.f);
        float l1 = as.y + ad.y; l1 = l1 > 0.f ? l1 : 0.2f * l1; l1 = fminf(l1, 80.f);
        float l2 = as.z + ad.z; l2 = l2 > 0.f ? l2 : 0.2f * l2; l2 = fminf(l2, 80.f);
        float l3 = as.w + ad.w; l3 = l3 > 0.f ? l3 : 0.2f * l3; l3 = fminf(l3, 80.f);
        float e0 = valid ? __expf(l0) : 0.f;
        float e1 = valid ? __expf(l1) : 0.f;
        float e2 = valid ? __expf(l2) : 0.f;
        float e3 = valid ? __expf(l3) : 0.f;
        float s0 = e0, s1 = e1, s2 = e2, s3 = e3;
#pragma unroll
        for (int o = 32; o; o >>= 1) {
            s0 += __shfl_xor(s0, o, 64); s1 += __shfl_xor(s1, o, 64);
            s2 += __shfl_xor(s2, o, 64); s3 += __shfl_xor(s3, o, 64);
        }
        float i0 = 1.f / (s0 + 1e-16f), i1 = 1.f / (s1 + 1e-16f);
        float i2 = 1.f / (s2 + 1e-16f), i3 = 1.f / (s3 + 1e-16f);
        float4 ex4; ex4.x = e0; ex4.y = e1; ex4.z = e2; ex4.w = e3;
        *(float4*)&exv[wv][lane * 4] = ex4;
        srcs[wv][lane] = src;
        lds_fence();
        for (int k = g; k < deg; k += 4) {
            float aex = exv[wv][k * 4 + h];
            int s2_ = srcs[wv][k];
            ushort4 u = *(const ushort4*)(XW0b + (size_t)(tb + s2_) * 64 + il * 4);
            floatx4 xv = { bfu(u.x), bfu(u.y), bfu(u.z), bfu(u.w) };
            av += aex * xv;
        }
        scale_h = (h == 0) ? i0 : (h == 1) ? i1 : (h == 2) ? i2 : i3;
    } else {
        float s0 = 0.f, s1 = 0.f, s2 = 0.f, s3 = 0.f;
        for (int e = rs + lane; e < re; e += 64) {
            int src = csr_src[e];
            float4 as = *(const float4*)(ALS0 + (size_t)(tb + src) * 4);
            float l0 = as.x + ad.x; l0 = l0 > 0.f ? l0 : 0.2f * l0; s0 += __expf(fminf(l0, 80.f));
            float l1 = as.y + ad.y; l1 = l1 > 0.f ? l1 : 0.2f * l1; s1 += __expf(fminf(l1, 80.f));
            float l2 = as.z + ad.z; l2 = l2 > 0.f ? l2 : 0.2f * l2; s2 += __expf(fminf(l2, 80.f));
            float l3 = as.w + ad.w; l3 = l3 > 0.f ? l3 : 0.2f * l3; s3 += __expf(fminf(l3, 80.f));
        }
#pragma unroll
        for (int o = 32; o; o >>= 1) {
            s0 += __shfl_xor(s0, o, 64); s1 += __shfl_xor(s1, o, 64);
            s2 += __shfl_xor(s2, o, 64); s3 += __shfl_xor(s3, o, 64);
        }
        float i0 = 1.f / (s0 + 1e-16f), i1 = 1.f / (s1 + 1e-16f);
        float i2 = 1.f / (s2 + 1e-16f), i3 = 1.f / (s3 + 1e-16f);
        float ih = (h == 0) ? i0 : (h == 1) ? i1 : (h == 2) ? i2 : i3;
        float adh = sel4(ad, h);
        for (int e0_ = rs; e0_ < re; e0_ += 4) {
            int e = e0_ + g;
            if (e < re) {
                int src = csr_src[e];
                float4 as = *(const float4*)(ALS0 + (size_t)(tb + src) * 4);
                float l = sel4(as, h) + adh; l = l > 0.f ? l : 0.2f * l;
                float a = __expf(fminf(l, 80.f)) * ih;
                ushort4 u = *(const ushort4*)(XW0b + (size_t)(tb + src) * 64 + il * 4);
                floatx4 xv = { bfu(u.x), bfu(u.y), bfu(u.z), bfu(u.w) };
                av += a * xv;
            }
        }
        scale_h = 1.f;
    }
#pragma unroll
    for (int o = 16; o <= 32; o <<= 1) {
#pragma unroll
        for (int j = 0; j < 4; j++) av[j] += __shfl_xor(av[j], o, 64);
    }
    if (g == 0) {
        int cb = il * 4;
        float v0 = av[0] * scale_h + b0[cb + 0]; v0 = v0 > 0.f ? v0 : (__expf(v0) - 1.f);
        float v1 = av[1] * scale_h + b0[cb + 1]; v1 = v1 > 0.f ? v1 : (__expf(v1) - 1.f);
        float v2 = av[2] * scale_h + b0[cb + 2]; v2 = v2 > 0.f ? v2 : (__expf(v2) - 1.f);
        float v3 = av[3] * scale_h + b0[cb + 3]; v3 = v3 > 0.f ? v3 : (__expf(v3) - 1.f);
        ushort4 o4;
        o4.x = f2bu(v0); o4.y = f2bu(v1); o4.z = f2bu(v2); o4.w = f2bu(v3);
        *(ushort4*)(H0b + (size_t)wid * 64 + cb) = o4;
    }
}

/* ---------------- layer-1 logits via MFMA: H0b @ [P1s|P1d]^T ------------- */
__global__ __launch_bounds__(256) void k_logits1(const bf16* __restrict__ H0b,
                                                 const float* __restrict__ P1s,
                                                 const float* __restrict__ P1d,
                                                 float* __restrict__ ALS1,
                                                 float* __restrict__ ALD1) {
    int tid = threadIdx.x;
    int wv = tid >> 6, lane = tid & 63;
    int tile = blockIdx.x * 4 + wv;
    if (tile >= NTILES) return;
    int rb = tile * 16;
    int m = lane & 15, quad = lane >> 4;
    short8 a0 = *(const short8*)(H0b + (size_t)(rb + m) * 64 + quad * 8);
    short8 a1 = *(const short8*)(H0b + (size_t)(rb + m) * 64 + 32 + quad * 8);
    short8 bb0, bb1;
#pragma unroll
    for (int j = 0; j < 8; j++) {
        int k0 = quad * 8 + j, k1 = 32 + quad * 8 + j;
        float v0 = 0.f, v1 = 0.f;
        if (m < 4)      { v0 = P1s[m * 64 + k0];       v1 = P1s[m * 64 + k1]; }
        else if (m < 8) { v0 = P1d[(m - 4) * 64 + k0]; v1 = P1d[(m - 4) * 64 + k1]; }
        bb0[j] = (short)f2bu(v0);
        bb1[j] = (short)f2bu(v1);
    }
    floatx4 acc = {0.f, 0.f, 0.f, 0.f};
    acc = __builtin_amdgcn_mfma_f32_16x16x32_bf16(a0, bb0, acc, 0, 0, 0);
    acc = __builtin_amdgcn_mfma_f32_16x16x32_bf16(a1, bb1, acc, 0, 0, 0);
#pragma unroll
    for (int r = 0; r < 4; r++) {
        int row = rb + quad * 4 + r;
        if (m < 4)      ALS1[row * 4 + m] = acc[r];
        else if (m < 8) ALD1[row * 4 + (m - 4)] = acc[r];
    }
}

/* ---------------- fused layer-1 + post1: softmax + aggregate + epilogue --
   Block = 1024 threads = 16 waves = 16 rows (one MFMA tile). Per-wave
   gather lands in padded LDS; wave 0 runs the W1-GEMM + mean/bias/ELU/LN
   epilogue with B-frags read from pre-transposed global W1tb (L2-hot). */
__global__ __launch_bounds__(1024) void k_fused1p(const int* __restrict__ rowst,
                                                  const int* __restrict__ csr_src,
                                                  const int* __restrict__ csr_eid,
                                                  const bf16* __restrict__ H0b,
                                                  const float* __restrict__ ALS1,
                                                  const float* __restrict__ ALD1,
                                                  const bf16* __restrict__ W1tb,
                                                  const float* __restrict__ b1,
                                                  const float* __restrict__ ln_g,
                                                  const float* __restrict__ ln_b,
                                                  bf16* __restrict__ HSb,
                                                  float* __restrict__ out_alpha) {
    __shared__ float exv[16][256];                    /* 16 KB */
    __shared__ int   srcs[16][64];                    /*  4 KB */
    __shared__ __align__(16) bf16 aggs[16][264];      /* 8.25 KB, +8 pad */
    int tid = threadIdx.x;
    int wv = tid >> 6;
    int lane = tid & 63;
    int wid = blockIdx.x * 16 + wv;
    int t = wid / N_NODES, n = wid % N_NODES;
    int rs = rowst[n], re = rowst[n + 1];
    int deg = re - rs;
    int tb = t * N_NODES;
    float4 ad = *(const float4*)(ALD1 + (size_t)wid * 4);
    int g = lane >> 4, il = lane & 15;
    bool do_out = (t == T_STEPS - 1);
    floatx4 acc4[4];
#pragma unroll
    for (int hh = 0; hh < 4; hh++) acc4[hh] = (floatx4){0.f, 0.f, 0.f, 0.f};
    float i0 = 1.f, i1 = 1.f, i2 = 1.f, i3 = 1.f;

    if (deg <= 64) {
        int e = rs + lane;
        bool valid = e < re;
        int src = csr_src[valid ? e : rs];
        float4 as = *(const float4*)(ALS1 + (size_t)(tb + src) * 4);
        float l0 = as.x + ad.x; l0 = l0 > 0.f ? l0 : 0.2f * l0; l0 = fminf(l0, 80.f);
        float l1 = as.y + ad.y; l1 = l1 > 0.f ? l1 : 0.2f * l1; l1 = fminf(l1, 80.f);
        float l2 = as.z + ad.z; l2 = l2 > 0.f ? l2 : 0.2f * l2; l2 = fminf(l2, 80.f);
        float l3 = as.w + ad.w; l3 = l3 > 0.f ? l3 : 0.2f * l3; l3 = fminf(l3, 80.f);
        float e0 = valid ? __expf(l0) : 0.f;
        float e1 = valid ? __expf(l1) : 0.f;
        float e2 = valid ? __expf(l2) : 0.f;
        float e3 = valid ? __expf(l3) : 0.f;
        float s0 = e0, s1 = e1, s2 = e2, s3 = e3;
#pragma unroll
        for (int o = 32; o; o >>= 1) {
            s0 += __shfl_xor(s0, o, 64); s1 += __shfl_xor(s1, o, 64);
            s2 += __shfl_xor(s2, o, 64); s3 += __shfl_xor(s3, o, 64);
        }
        i0 = 1.f / (s0 + 1e-16f); i1 = 1.f / (s1 + 1e-16f);
        i2 = 1.f / (s2 + 1e-16f); i3 = 1.f / (s3 + 1e-16f);
        float4 ex4; ex4.x = e0; ex4.y = e1; ex4.z = e2; ex4.w = e3;
        *(float4*)&exv[wv][lane * 4] = ex4;
        srcs[wv][lane] = src;
        lds_fence();
        for (int k = g; k < deg; k += 4) {
            float4 ex = *(const float4*)&exv[wv][k * 4];
            int s2_ = srcs[wv][k];
            ushort4 u = *(const ushort4*)(H0b + (size_t)(tb + s2_) * 64 + il * 4);
            floatx4 xv = { bfu(u.x), bfu(u.y), bfu(u.z), bfu(u.w) };
            acc4[0] += ex.x * xv;
            acc4[1] += ex.y * xv;
            acc4[2] += ex.z * xv;
            acc4[3] += ex.w * xv;
        }
        if (do_out && valid) {
            int eid = csr_eid[e];
            float4 o4; o4.x = e0 * i0; o4.y = e1 * i1; o4.z = e2 * i2; o4.w = e3 * i3;
            *(float4*)(out_alpha + (size_t)eid * 4) = o4;
        }
    } else {
        float s0 = 0.f, s1 = 0.f, s2 = 0.f, s3 = 0.f;
        for (int e = rs + lane; e < re; e += 64) {
            int src = csr_src[e];
            float4 as = *(const float4*)(ALS1 + (size_t)(tb + src) * 4);
            float l0 = as.x + ad.x; l0 = l0 > 0.f ? l0 : 0.2f * l0; s0 += __expf(fminf(l0, 80.f));
            float l1 = as.y + ad.y; l1 = l1 > 0.f ? l1 : 0.2f * l1; s1 += __expf(fminf(l1, 80.f));
            float l2 = as.z + ad.z; l2 = l2 > 0.f ? l2 : 0.2f * l2; s2 += __expf(fminf(l2, 80.f));
            float l3 = as.w + ad.w; l3 = l3 > 0.f ? l3 : 0.2f * l3; s3 += __expf(fminf(l3, 80.f));
        }
#pragma unroll
        for (int o = 32; o; o >>= 1) {
            s0 += __shfl_xor(s0, o, 64); s1 += __shfl_xor(s1, o, 64);
            s2 += __shfl_xor(s2, o, 64); s3 += __shfl_xor(s3, o, 64);
        }
        float j0 = 1.f / (s0 + 1e-16f), j1 = 1.f / (s1 + 1e-16f);
        float j2 = 1.f / (s2 + 1e-16f), j3 = 1.f / (s3 + 1e-16f);
        for (int e0_ = rs; e0_ < re; e0_ += 4) {
            int e = e0_ + g;
            if (e < re) {
                int src = csr_src[e];
                float4 as = *(const float4*)(ALS1 + (size_t)(tb + src) * 4);
                float l0 = as.x + ad.x; l0 = l0 > 0.f ? l0 : 0.2f * l0;
                float l1 = as.y + ad.y; l1 = l1 > 0.f ? l1 : 0.2f * l1;
                float l2 = as.z + ad.z; l2 = l2 > 0.f ? l2 : 0.2f * l2;
                float l3 = as.w + ad.w; l3 = l3 > 0.f ? l3 : 0.2f * l3;
                float al0 = __expf(fminf(l0, 80.f)) * j0;
                float al1 = __expf(fminf(l1, 80.f)) * j1;
                float al2 = __expf(fminf(l2, 80.f)) * j2;
                float al3 = __expf(fminf(l3, 80.f)) * j3;
                if (do_out && il == 0) {
                    int eid = csr_eid[e];
                    float4 o4; o4.x = al0; o4.y = al1; o4.z = al2; o4.w = al3;
                    *(float4*)(out_alpha + (size_t)eid * 4) = o4;
                }
                ushort4 u = *(const ushort4*)(H0b + (size_t)(tb + src) * 64 + il * 4);
                floatx4 xv = { bfu(u.x), bfu(u.y), bfu(u.z), bfu(u.w) };
                acc4[0] += al0 * xv;
                acc4[1] += al1 * xv;
                acc4[2] += al2 * xv;
                acc4[3] += al3 * xv;
            }
        }
        i0 = i1 = i2 = i3 = 1.f;
    }
    acc4[0] *= i0; acc4[1] *= i1; acc4[2] *= i2; acc4[3] *= i3;
#pragma unroll
    for (int o = 16; o <= 32; o <<= 1)
#pragma unroll
        for (int hh = 0; hh < 4; hh++)
#pragma unroll
            for (int j = 0; j < 4; j++)
                acc4[hh][j] += __shfl_xor(acc4[hh][j], o, 64);
    if (g == 0) {
        int cb = il * 4;
#pragma unroll
        for (int hh = 0; hh < 4; hh++) {
            ushort4 o4;
            o4.x = f2bu(acc4[hh][0]); o4.y = f2bu(acc4[hh][1]);
            o4.z = f2bu(acc4[hh][2]); o4.w = f2bu(acc4[hh][3]);
            *(ushort4*)(&aggs[wv][hh * 64 + cb]) = o4;
        }
    }
    __syncthreads();
    /* epilogue: wave 0 computes the 16-row tile: AGG @ Wbig + mean/bias/ELU/LN */
    if (wv == 0) {
        int m = lane & 15, quad = lane >> 4;
        short8 af[8];
#pragma unroll
        for (int kb = 0; kb < 8; kb++)
            af[kb] = *(const short8*)(&aggs[m][kb * 32 + quad * 8]);
        floatx4 acc[4];
#pragma unroll
        for (int ct = 0; ct < 4; ct++) {
            const bf16* wrow = W1tb + (ct * 16 + m) * 256 + quad * 8;
            floatx4 a = {0.f, 0.f, 0.f, 0.f};
#pragma unroll
            for (int kb = 0; kb < 8; kb++) {
                short8 bf = *(const short8*)(wrow + kb * 32);
                a = __builtin_amdgcn_mfma_f32_16x16x32_bf16(af[kb], bf, a, 0, 0, 0);
            }
            acc[ct] = a;
        }
        float b1v[4], ggv[4], bbv[4];
#pragma unroll
        for (int ct = 0; ct < 4; ct++) {
            b1v[ct] = b1[ct * 16 + m]; ggv[ct] = ln_g[ct * 16 + m]; bbv[ct] = ln_b[ct * 16 + m];
        }
        int rb = blockIdx.x * 16;
#pragma unroll
        for (int r = 0; r < 4; r++) {
            float v[4];
            float s = 0.f;
#pragma unroll
            for (int ct = 0; ct < 4; ct++) {
                float t_ = acc[ct][r] * 0.25f + b1v[ct];
                t_ = t_ > 0.f ? t_ : (__expf(t_) - 1.f);
                v[ct] = t_; s += t_;
            }
#pragma unroll
            for (int o = 8; o; o >>= 1) s += __shfl_xor(s, o, 64);
            float mu = s * (1.f / 64.f);
            float q = 0.f;
#pragma unroll
            for (int ct = 0; ct < 4; ct++) { float d = v[ct] - mu; q += d * d; }
#pragma unroll
            for (int o = 8; o; o >>= 1) q += __shfl_xor(q, o, 64);
            float rinv = rsqrtf(q * (1.f / 64.f) + 1e-5f);
            int row = rb + quad * 4 + r;
#pragma unroll
            for (int ct = 0; ct < 4; ct++)
                HSb[(size_t)row * 64 + ct * 16 + m] =
                    __float2bfloat16((v[ct] - mu) * rinv * ggv[ct] + bbv[ct]);
        }
    }
}

/* ---------------- GRU: ALL steps fused in one MFMA kernel ---------------- */
__global__ __launch_bounds__(256) void k_gru(const bf16* __restrict__ HSb,
                                             const float* __restrict__ W_ih,
                                             const float* __restrict__ b_ih,
                                             const float* __restrict__ W_hh,
                                             const float* __restrict__ b_hh,
                                             float* __restrict__ outh) {
    __shared__ __align__(16) bf16 wi[192 * 64];        /* 24 KB, [j][k] */
    __shared__ __align__(16) bf16 wh[192 * 64];        /* 24 KB, [j][k] */
    __shared__ __align__(16) bf16 hbuf[4][16 * 72];    /* 9 KB, stride-72 pad */
    int tid = threadIdx.x;
    for (int i = tid; i < 12288; i += 256) {
        wi[i] = __float2bfloat16(W_ih[i]);
        wh[i] = __float2bfloat16(W_hh[i]);
    }
    __syncthreads();
    int wv = tid >> 6, lane = tid & 63;
    int tile = blockIdx.x * 4 + wv;
    if (tile >= N_NODES / 16) return;
    int rb = tile * 16;
    int m = lane & 15, quad = lane >> 4;
    bf16* hb = &hbuf[wv][0];
    float bi_[12], bh_[12];
#pragma unroll
    for (int ct = 0; ct < 12; ct++) { bi_[ct] = b_ih[ct * 16 + m]; bh_[ct] = b_hh[ct * 16 + m]; }
    float hprev[4][4];
#pragma unroll
    for (int ct = 0; ct < 4; ct++)
#pragma unroll
        for (int r = 0; r < 4; r++) hprev[ct][r] = 0.f;

    for (int t = 0; t < T_STEPS; t++) {
        const bf16* xr = HSb + ((size_t)t * N_NODES + rb + m) * 64;
        short8 ax0 = *(const short8*)(xr + quad * 8);
        short8 ax1 = *(const short8*)(xr + 32 + quad * 8);
        short8 ah0, ah1;
        if (t > 0) {
            ah0 = *(const short8*)(hb + m * 72 + quad * 8);
            ah1 = *(const short8*)(hb + m * 72 + 32 + quad * 8);
        }
        floatx4 rz[8];
        floatx4 gg_i[4];
        floatx4 gg_h[4];
#pragma unroll
        for (int ct = 0; ct < 8; ct++) {
            int cb = ct * 16;
            short8 b0 = *(const short8*)(wi + (cb + m) * 64 + quad * 8);
            short8 b1 = *(const short8*)(wi + (cb + m) * 64 + 32 + quad * 8);
            floatx4 a = {0.f, 0.f, 0.f, 0.f};
            a = __builtin_amdgcn_mfma_f32_16x16x32_bf16(ax0, b0, a, 0, 0, 0);
            a = __builtin_amdgcn_mfma_f32_16x16x32_bf16(ax1, b1, a, 0, 0, 0);
            if (t > 0) {
                short8 c0 = *(const short8*)(wh + (cb + m) * 64 + quad * 8);
                short8 c1 = *(const short8*)(wh + (cb + m) * 64 + 32 + quad * 8);
                a = __builtin_amdgcn_mfma_f32_16x16x32_bf16(ah0, c0, a, 0, 0, 0);
                a = __builtin_amdgcn_mfma_f32_16x16x32_bf16(ah1, c1, a, 0, 0, 0);
            }
            rz[ct] = a;
        }
#pragma unroll
        for (int ct = 0; ct < 4; ct++) {
            int cb = (ct + 8) * 16;
            short8 b0 = *(const short8*)(wi + (cb + m) * 64 + quad * 8);
            short8 b1 = *(const short8*)(wi + (cb + m) * 64 + 32 + quad * 8);
            floatx4 a = {0.f, 0.f, 0.f, 0.f};
            a = __builtin_amdgcn_mfma_f32_16x16x32_bf16(ax0, b0, a, 0, 0, 0);
            a = __builtin_amdgcn_mfma_f32_16x16x32_bf16(ax1, b1, a, 0, 0, 0);
            gg_i[ct] = a;
            floatx4 c = {0.f, 0.f, 0.f, 0.f};
            if (t > 0) {
                short8 c0 = *(const short8*)(wh + (cb + m) * 64 + quad * 8);
                short8 c1 = *(const short8*)(wh + (cb + m) * 64 + 32 + quad * 8);
                c = __builtin_amdgcn_mfma_f32_16x16x32_bf16(ah0, c0, c, 0, 0, 0);
                c = __builtin_amdgcn_mfma_f32_16x16x32_bf16(ah1, c1, c, 0, 0, 0);
            }
            gg_h[ct] = c;
        }
#pragma unroll
        for (int ct = 0; ct < 4; ct++) {
#pragma unroll
            for (int r = 0; r < 4; r++) {
                float rr = 1.f / (1.f + __expf(-(rz[ct][r] + bi_[ct] + bh_[ct])));
                float z  = 1.f / (1.f + __expf(-(rz[ct + 4][r] + bi_[ct + 4] + bh_[ct + 4])));
                float g  = tanhf(gg_i[ct][r] + bi_[ct + 8] + rr * (gg_h[ct][r] + bh_[ct + 8]));
                hprev[ct][r] = (1.f - z) * g + z * hprev[ct][r];
            }
        }
        if (t < T_STEPS - 1) {
#pragma unroll
            for (int ct = 0; ct < 4; ct++)
#pragma unroll
                for (int r = 0; r < 4; r++)
                    hb[(quad * 4 + r) * 72 + ct * 16 + m] = __float2bfloat16(hprev[ct][r]);
            lds_fence();
        }
    }
#pragma unroll
    for (int ct = 0; ct < 4; ct++)
#pragma unroll
        for (int r = 0; r < 4; r++)
            outh[(size_t)(rb + quad * 4 + r) * 64 + ct * 16 + m] = hprev[ct][r];
}

/* ---------------- output writer (fp32) ---------------- */

__global__ void k_out_ei(const int* __restrict__ ei, float* __restrict__ out) {
    int i = blockIdx.x * blockDim.x + threadIdx.x;
    if (i >= 2 * EP) return;
    int v;
    if (i < EP) {
        v = (i < E_EDGES) ? ei[i] : (i - E_EDGES);                 // src row
    } else {
        int jj = i - EP;
        v = (jj < E_EDGES) ? ei[E_EDGES + jj] : (jj - E_EDGES);    // dst row
    }
    out[i] = (float)v;
}

/* ---------------- launch ---------------- */

extern "C" void kernel_launch(void* const* d_in, const int* in_sizes, int n_in,
                              void* d_out, int out_size, void* d_ws, size_t ws_size,
                              hipStream_t stream) {
    const float* x      = (const float*)d_in[0];
    const int*   ei     = (const int*)d_in[1];
    const float* W0     = (const float*)d_in[2];
    const float* a_src0 = (const float*)d_in[3];
    const float* a_dst0 = (const float*)d_in[4];
    const float* b0     = (const float*)d_in[5];
    const float* W1     = (const float*)d_in[6];
    const float* a_src1 = (const float*)d_in[7];
    const float* a_dst1 = (const float*)d_in[8];
    const float* b1     = (const float*)d_in[9];
    const float* ln_g   = (const float*)d_in[10];
    const float* ln_b   = (const float*)d_in[11];
    const float* W_ih   = (const float*)d_in[12];
    const float* W_hh   = (const float*)d_in[13];
    const float* b_ih   = (const float*)d_in[14];
    const float* b_hh   = (const float*)d_in[15];
    float* out = (float*)d_out;

    char* w = (char*)d_ws;
    size_t off = 0;
    auto take = [&](size_t bytes) -> void* {
        void* p = w + off;
        off = (off + bytes + 255) & ~(size_t)255;
        return p;
    };
    int*   counts  = (int*)take(N_NODES * 4);
    int*   fill    = (int*)take(N_NODES * 4);
    int*   rowst   = (int*)take((N_NODES + 1) * 4);
    int*   csr_src = (int*)take((size_t)EP * 4);
    int*   csr_eid = (int*)take((size_t)EP * 4);
    bf16*  XW0b    = (bf16*)take((size_t)TN * 64 * 2);
    float* ALS0    = (float*)take((size_t)TN * 4 * 4);
    float* ALD0    = (float*)take((size_t)TN * 4 * 4);
    bf16*  H0b     = (bf16*)take((size_t)TN * 64 * 2);
    float* P1s     = (float*)take(256 * 4);
    float* P1d     = (float*)take(256 * 4);
    bf16*  W1tb    = (bf16*)take(64 * 256 * 2);
    float* ALS1    = (float*)take((size_t)TN * 4 * 4);
    float* ALD1    = (float*)take((size_t)TN * 4 * 4);
    bf16*  HSb     = (bf16*)take((size_t)TN * 64 * 2);
    (void)ws_size; (void)in_sizes; (void)n_in; (void)out_size;

    const int B = 256;
    /* CSR build + prep */
    hipMemsetAsync(counts, 0, N_NODES * 4, stream);
    hipMemsetAsync(fill, 0, N_NODES * 4, stream);
    k_count<<<(EP + B - 1) / B, B, 0, stream>>>(ei, counts);
    k_scan<<<1, 1024, 0, stream>>>(counts, rowst);
    k_scatter<<<(EP + B - 1) / B, B, 0, stream>>>(ei, rowst, fill, csr_src, csr_eid);
    k_prep1<<<1, B, 0, stream>>>(W1, a_src1, a_dst1, P1s, P1d, W1tb);

    const int GT = (NTILES + 3) / 4;   /* 938 blocks for 16-row-tile MFMA kernels */
    /* GAT layer 0 */
    k_gemm0<<<GT, B, 0, stream>>>(x, W0, a_src0, a_dst0, XW0b, ALS0, ALD0);
    k_fused0<<<TN / 4, B, 0, stream>>>(rowst, csr_src, XW0b, ALS0, ALD0, b0, H0b);
    k_logits1<<<GT, B, 0, stream>>>(H0b, P1s, P1d, ALS1, ALD1);

    /* GAT layer 1 + epilogue fused (16 rows per 1024-thread block) */
    k_fused1p<<<TN / 16, 1024, 0, stream>>>(rowst, csr_src, csr_eid, H0b, ALS1, ALD1,
                                            W1tb, b1, ln_g, ln_b, HSb,
                                            out + (size_t)N_NODES * HID);

    /* GRU: one fused kernel, all 6 steps, writes hT to out */
    k_gru<<<(N_NODES / 16 + 3) / 4, B, 0, stream>>>(HSb, W_ih, b_ih, W_hh, b_hh, out);

    /* edge-index output */
    k_out_ei<<<(2 * EP + B - 1) / B, B, 0, stream>>>(ei, out + (size_t)N_NODES * HID + (size_t)EP * HEADS);
}

// Round 14
// 294.410 us; speedup vs baseline: 1.0588x; 1.0588x over previous
//
#include <hip/hip_runtime.h>
#include <hip/hip_bf16.h>
#include <cstdint>
#include <cstddef>

#define N_NODES 10000
#define T_STEPS 6
#define F_IN    64
#define HID     64
#define HEADS   4
#define E_EDGES 160000
#define EP      (E_EDGES + N_NODES)   /* 170000 edges incl self-loops */
#define TN      (T_STEPS * N_NODES)   /* 60000 */
#define NTILES  (TN / 16)             /* 3750 */

typedef __hip_bfloat16 bf16;
typedef __attribute__((ext_vector_type(8))) short short8;
typedef __attribute__((ext_vector_type(4))) float floatx4;

__device__ __forceinline__ float b2f(bf16 v) { return __bfloat162float(v); }
__device__ __forceinline__ float bfu(unsigned short s) { return __uint_as_float((unsigned)s << 16); }
__device__ __forceinline__ unsigned short f2bu(float f) {
    bf16 b = __float2bfloat16(f);
    return *(unsigned short*)&b;
}
__device__ __forceinline__ float sel4(float4 v, int h) {
    float r = v.x;
    r = (h == 1) ? v.y : r;
    r = (h == 2) ? v.z : r;
    r = (h == 3) ? v.w : r;
    return r;
}
__device__ __forceinline__ void lds_fence() {
    asm volatile("s_waitcnt lgkmcnt(0)" ::: "memory");
}

/* ---------------- CSR build ---------------- */

__global__ void k_count(const int* ei, int* counts) {
    int e = blockIdx.x * blockDim.x + threadIdx.x;
    if (e >= EP) return;
    int dst = (e < E_EDGES) ? ei[E_EDGES + e] : (e - E_EDGES);
    atomicAdd(&counts[dst], 1);
}

__global__ void k_scan(const int* counts, int* rowstart) {
    __shared__ int part[1024];
    int tid = threadIdx.x;
    const int chunk = (N_NODES + 1023) / 1024;  // 10
    int base = tid * chunk;
    int s = 0;
    for (int i = 0; i < chunk; i++) { int idx = base + i; if (idx < N_NODES) s += counts[idx]; }
    part[tid] = s;
    __syncthreads();
    for (int off = 1; off < 1024; off <<= 1) {
        int v = (tid >= off) ? part[tid - off] : 0;
        __syncthreads();
        part[tid] += v;
        __syncthreads();
    }
    int run = (tid == 0) ? 0 : part[tid - 1];
    for (int i = 0; i < chunk; i++) {
        int idx = base + i;
        if (idx < N_NODES) { rowstart[idx] = run; run += counts[idx]; }
    }
    if (tid == 0) rowstart[N_NODES] = EP;
}

__global__ void k_scatter(const int* ei, const int* rowstart, int* fill,
                          int* csr_src, int* csr_eid) {
    int e = blockIdx.x * blockDim.x + threadIdx.x;
    if (e >= EP) return;
    int src = (e < E_EDGES) ? ei[e] : (e - E_EDGES);
    int dst = (e < E_EDGES) ? ei[E_EDGES + e] : (e - E_EDGES);
    int pos = rowstart[dst] + atomicAdd(&fill[dst], 1);
    csr_src[pos] = src;
    csr_eid[pos] = e;
}

/* ---------------- prep: P-matrices + transposed bf16 W1 ---------------- */

__global__ __launch_bounds__(256) void k_prep1(const float* __restrict__ W1,
                                               const float* __restrict__ a_src1,
                                               const float* __restrict__ a_dst1,
                                               float* __restrict__ P1s,
                                               float* __restrict__ P1d,
                                               bf16* __restrict__ W1tb) {
    int tid = threadIdx.x;
    int h = tid >> 6, k = tid & 63;
    float ps = 0.f, pd = 0.f;
    for (int c = 0; c < 64; c++) {
        float wv = W1[k * 256 + h * 64 + c];
        ps += wv * a_src1[h * 64 + c];
        pd += wv * a_dst1[h * 64 + c];
    }
    P1s[h * 64 + k] = ps;
    P1d[h * 64 + k] = pd;
    /* W1tb[c][K] = W1[K&63][ (K>>6)*64 + c ]  (Wbig^T, bf16) */
    for (int i = tid; i < 64 * 256; i += 256) {
        int c = i >> 8, K = i & 255;
        W1tb[i] = __float2bfloat16(W1[(K & 63) * 256 + (K >> 6) * 64 + c]);
    }
}

/* ---------------- GAT layer 0 GEMM (MFMA) ---------------- */
__global__ __launch_bounds__(256) void k_gemm0(const float* __restrict__ x,
                                               const float* __restrict__ W0,
                                               const float* __restrict__ a_src0,
                                               const float* __restrict__ a_dst0,
                                               bf16* __restrict__ XW0b,
                                               float* __restrict__ ALS0,
                                               float* __restrict__ ALD0) {
    __shared__ __align__(16) bf16 wt[64 * 64];   /* [c][k], 8 KB */
    int tid = threadIdx.x;
    for (int i = tid; i < 4096; i += 256) {
        int c = i >> 6, k = i & 63;
        wt[i] = __float2bfloat16(W0[k * 64 + c]);
    }
    __syncthreads();
    int wv = tid >> 6, lane = tid & 63;
    int tile = blockIdx.x * 4 + wv;
    if (tile >= NTILES) return;
    int rb = tile * 16;
    int m = lane & 15, quad = lane >> 4;
    int row = rb + m;
    int t = row / N_NODES, n = row - t * N_NODES;
    const float* xr = x + ((size_t)n * T_STEPS + t) * F_IN + quad * 8;
    short8 a0, a1;
#pragma unroll
    for (int j = 0; j < 8; j++) {
        a0[j] = (short)f2bu(xr[j]);
        a1[j] = (short)f2bu(xr[32 + j]);
    }
    floatx4 acc[4];
#pragma unroll
    for (int ct = 0; ct < 4; ct++) {
        short8 bb0 = *(const short8*)(wt + (ct * 16 + m) * 64 + quad * 8);
        short8 bb1 = *(const short8*)(wt + (ct * 16 + m) * 64 + 32 + quad * 8);
        floatx4 a = {0.f, 0.f, 0.f, 0.f};
        a = __builtin_amdgcn_mfma_f32_16x16x32_bf16(a0, bb0, a, 0, 0, 0);
        a = __builtin_amdgcn_mfma_f32_16x16x32_bf16(a1, bb1, a, 0, 0, 0);
        acc[ct] = a;
    }
#pragma unroll
    for (int ct = 0; ct < 4; ct++) {
        float as0 = a_src0[ct * 16 + m], ad0 = a_dst0[ct * 16 + m];
#pragma unroll
        for (int r = 0; r < 4; r++) {
            int orow = rb + quad * 4 + r;
            float v = acc[ct][r];
            XW0b[(size_t)orow * 64 + ct * 16 + m] = __float2bfloat16(v);
            float ps = v * as0, pd = v * ad0;
#pragma unroll
            for (int o = 8; o; o >>= 1) { ps += __shfl_xor(ps, o, 64); pd += __shfl_xor(pd, o, 64); }
            if (m == 0) { ALS0[orow * 4 + ct] = ps; ALD0[orow * 4 + ct] = pd; }
        }
    }
}

/* ---------------- fused layer-0: softmax + accumulate ---------------- */
__global__ __launch_bounds__(256) void k_fused0(const int* __restrict__ rowst,
                                                const int* __restrict__ csr_src,
                                                const bf16* __restrict__ XW0b,
                                                const float* __restrict__ ALS0,
                                                const float* __restrict__ ALD0,
                                                const float* __restrict__ b0,
                                                bf16* __restrict__ H0b) {
    __shared__ float exv[4][256];
    __shared__ int   srcs[4][64];
    int tid = threadIdx.x;
    int wv = tid >> 6;
    int wid = blockIdx.x * 4 + wv;
    int lane = tid & 63;
    int t = wid / N_NODES, n = wid % N_NODES;
    int rs = rowst[n], re = rowst[n + 1];
    int deg = re - rs;
    int tb = t * N_NODES;
    float4 ad = *(const float4*)(ALD0 + (size_t)wid * 4);
    int g = lane >> 4, il = lane & 15;
    int h = il >> 2;
    floatx4 av = {0.f, 0.f, 0.f, 0.f};
    float scale_h;

    if (deg <= 64) {
        int e = rs + lane;
        bool valid = e < re;
        int src = csr_src[valid ? e : rs];
        float4 as = *(const float4*)(ALS0 + (size_t)(tb + src) * 4);
        float l0 = as.x + ad.x; l0 = l0 > 0.f ? l0 : 0.2f * l0; l0 = fminf(l0, 80.f);
        float l1 = as.y + ad.y; l1 = l1 > 0.f ? l1 : 0.2f * l1; l1 = fminf(l1, 80.f);
        float l2 = as.z + ad.z; l2 = l2 > 0.f ? l2 : 0.2f * l2; l2 = fminf(l2, 80.f);
        float l3 = as.w + ad.w; l3 = l3 > 0.f ? l3 : 0.2f * l3; l3 = fminf(l3, 80.f);
        float e0 = valid ? __expf(l0) : 0.f;
        float e1 = valid ? __expf(l1) : 0.f;
        float e2 = valid ? __expf(l2) : 0.f;
        float e3 = valid ? __expf(l3) : 0.f;
        float s0 = e0, s1 = e1, s2 = e2, s3 = e3;
#pragma unroll
        for (int o = 32; o; o >>= 1) {
            s0 += __shfl_xor(s0, o, 64); s1 += __shfl_xor(s1, o, 64);
            s2 += __shfl_xor(s2, o, 64); s3 += __shfl_xor(s3, o, 64);
        }
        float i0 = 1.f / (s0 + 1e-16f), i1 = 1.f / (s1 + 1e-16f);
        float i2 = 1.f / (s2 + 1e-16f), i3 = 1.f / (s3 + 1e-16f);
        float4 ex4; ex4.x = e0; ex4.y = e1; ex4.z = e2; ex4.w = e3;
        *(float4*)&exv[wv][lane * 4] = ex4;
        srcs[wv][lane] = src;
        lds_fence();
        for (int k = g; k < deg; k += 4) {
            float aex = exv[wv][k * 4 + h];
            int s2_ = srcs[wv][k];
            ushort4 u = *(const ushort4*)(XW0b + (size_t)(tb + s2_) * 64 + il * 4);
            floatx4 xv = { bfu(u.x), bfu(u.y), bfu(u.z), bfu(u.w) };
            av += aex * xv;
        }
        scale_h = (h == 0) ? i0 : (h == 1) ? i1 : (h == 2) ? i2 : i3;
    } else {
        float s0 = 0.f, s1 = 0.f, s2 = 0.f, s3 = 0.f;
        for (int e = rs + lane; e < re; e += 64) {
            int src = csr_src[e];
            float4 as = *(const float4*)(ALS0 + (size_t)(tb + src) * 4);
            float l0 = as.x + ad.x; l0 = l0 > 0.f ? l0 : 0.2f * l0; s0 += __expf(fminf(l0, 80.f));
            float l1 = as.y + ad.y; l1 = l1 > 0.f ? l1 : 0.2f * l1; s1 += __expf(fminf(l1, 80.f));
            float l2 = as.z + ad.z; l2 = l2 > 0.f ? l2 : 0.2f * l2; s2 += __expf(fminf(l2, 80.f));
            float l3 = as.w + ad.w; l3 = l3 > 0.f ? l3 : 0.2f * l3; s3 += __expf(fminf(l3, 80.f));
        }
#pragma unroll
        for (int o = 32; o; o >>= 1) {
            s0 += __shfl_xor(s0, o, 64); s1 += __shfl_xor(s1, o, 64);
            s2 += __shfl_xor(s2, o, 64); s3 += __shfl_xor(s3, o, 64);
        }
        float i0 = 1.f / (s0 + 1e-16f), i1 = 1.f / (s1 + 1e-16f);
        float i2 = 1.f / (s2 + 1e-16f), i3 = 1.f / (s3 + 1e-16f);
        float ih = (h == 0) ? i0 : (h == 1) ? i1 : (h == 2) ? i2 : i3;
        float adh = sel4(ad, h);
        for (int e0_ = rs; e0_ < re; e0_ += 4) {
            int e = e0_ + g;
            if (e < re) {
                int src = csr_src[e];
                float4 as = *(const float4*)(ALS0 + (size_t)(tb + src) * 4);
                float l = sel4(as, h) + adh; l = l > 0.f ? l : 0.2f * l;
                float a = __expf(fminf(l, 80.f)) * ih;
                ushort4 u = *(const ushort4*)(XW0b + (size_t)(tb + src) * 64 + il * 4);
                floatx4 xv = { bfu(u.x), bfu(u.y), bfu(u.z), bfu(u.w) };
                av += a * xv;
            }
        }
        scale_h = 1.f;
    }
#pragma unroll
    for (int o = 16; o <= 32; o <<= 1) {
#pragma unroll
        for (int j = 0; j < 4; j++) av[j] += __shfl_xor(av[j], o, 64);
    }
    if (g == 0) {
        int cb = il * 4;
        float v0 = av[0] * scale_h + b0[cb + 0]; v0 = v0 > 0.f ? v0 : (__expf(v0) - 1.f);
        float v1 = av[1] * scale_h + b0[cb + 1]; v1 = v1 > 0.f ? v1 : (__expf(v1) - 1.f);
        float v2 = av[2] * scale_h + b0[cb + 2]; v2 = v2 > 0.f ? v2 : (__expf(v2) - 1.f);
        float v3 = av[3] * scale_h + b0[cb + 3]; v3 = v3 > 0.f ? v3 : (__expf(v3) - 1.f);
        ushort4 o4;
        o4.x = f2bu(v0); o4.y = f2bu(v1); o4.z = f2bu(v2); o4.w = f2bu(v3);
        *(ushort4*)(H0b + (size_t)wid * 64 + cb) = o4;
    }
}

/* ---------------- layer-1 logits via MFMA: H0b @ [P1s|P1d]^T ------------- */
__global__ __launch_bounds__(256) void k_logits1(const bf16* __restrict__ H0b,
                                                 const float* __restrict__ P1s,
                                                 const float* __restrict__ P1d,
                                                 float* __restrict__ ALS1,
                                                 float* __restrict__ ALD1) {
    int tid = threadIdx.x;
    int wv = tid >> 6, lane = tid & 63;
    int tile = blockIdx.x * 4 + wv;
    if (tile >= NTILES) return;
    int rb = tile * 16;
    int m = lane & 15, quad = lane >> 4;
    short8 a0 = *(const short8*)(H0b + (size_t)(rb + m) * 64 + quad * 8);
    short8 a1 = *(const short8*)(H0b + (size_t)(rb + m) * 64 + 32 + quad * 8);
    short8 bb0, bb1;
#pragma unroll
    for (int j = 0; j < 8; j++) {
        int k0 = quad * 8 + j, k1 = 32 + quad * 8 + j;
        float v0 = 0.f, v1 = 0.f;
        if (m < 4)      { v0 = P1s[m * 64 + k0];       v1 = P1s[m * 64 + k1]; }
        else if (m < 8) { v0 = P1d[(m - 4) * 64 + k0]; v1 = P1d[(m - 4) * 64 + k1]; }
        bb0[j] = (short)f2bu(v0);
        bb1[j] = (short)f2bu(v1);
    }
    floatx4 acc = {0.f, 0.f, 0.f, 0.f};
    acc = __builtin_amdgcn_mfma_f32_16x16x32_bf16(a0, bb0, acc, 0, 0, 0);
    acc = __builtin_amdgcn_mfma_f32_16x16x32_bf16(a1, bb1, acc, 0, 0, 0);
#pragma unroll
    for (int r = 0; r < 4; r++) {
        int row = rb + quad * 4 + r;
        if (m < 4)      ALS1[row * 4 + m] = acc[r];
        else if (m < 8) ALD1[row * 4 + (m - 4)] = acc[r];
    }
}

/* ---------------- fused layer-1: softmax + aggregate (+alpha out t=5) ---- */
__global__ __launch_bounds__(256) void k_fused1(const int* __restrict__ rowst,
                                                const int* __restrict__ csr_src,
                                                const int* __restrict__ csr_eid,
                                                const bf16* __restrict__ H0b,
                                                const float* __restrict__ ALS1,
                                                const float* __restrict__ ALD1,
                                                bf16* __restrict__ AGG1b,
                                                float* __restrict__ out_alpha) {
    __shared__ float exv[4][256];
    __shared__ int   srcs[4][64];
    int tid = threadIdx.x;
    int wv = tid >> 6;
    int wid = blockIdx.x * 4 + wv;
    int lane = tid & 63;
    int t = wid / N_NODES, n = wid % N_NODES;
    int rs = rowst[n], re = rowst[n + 1];
    int deg = re - rs;
    int tb = t * N_NODES;
    float4 ad = *(const float4*)(ALD1 + (size_t)wid * 4);
    int g = lane >> 4, il = lane & 15;
    bool do_out = (t == T_STEPS - 1);
    floatx4 acc4[4];
#pragma unroll
    for (int hh = 0; hh < 4; hh++) acc4[hh] = (floatx4){0.f, 0.f, 0.f, 0.f};
    float i0 = 1.f, i1 = 1.f, i2 = 1.f, i3 = 1.f;

    if (deg <= 64) {
        int e = rs + lane;
        bool valid = e < re;
        int src = csr_src[valid ? e : rs];
        float4 as = *(const float4*)(ALS1 + (size_t)(tb + src) * 4);
        float l0 = as.x + ad.x; l0 = l0 > 0.f ? l0 : 0.2f * l0; l0 = fminf(l0, 80.f);
        float l1 = as.y + ad.y; l1 = l1 > 0.f ? l1 : 0.2f * l1; l1 = fminf(l1, 80.f);
        float l2 = as.z + ad.z; l2 = l2 > 0.f ? l2 : 0.2f * l2; l2 = fminf(l2, 80.f);
        float l3 = as.w + ad.w; l3 = l3 > 0.f ? l3 : 0.2f * l3; l3 = fminf(l3, 80.f);
        float e0 = valid ? __expf(l0) : 0.f;
        float e1 = valid ? __expf(l1) : 0.f;
        float e2 = valid ? __expf(l2) : 0.f;
        float e3 = valid ? __expf(l3) : 0.f;
        float s0 = e0, s1 = e1, s2 = e2, s3 = e3;
#pragma unroll
        for (int o = 32; o; o >>= 1) {
            s0 += __shfl_xor(s0, o, 64); s1 += __shfl_xor(s1, o, 64);
            s2 += __shfl_xor(s2, o, 64); s3 += __shfl_xor(s3, o, 64);
        }
        i0 = 1.f / (s0 + 1e-16f); i1 = 1.f / (s1 + 1e-16f);
        i2 = 1.f / (s2 + 1e-16f); i3 = 1.f / (s3 + 1e-16f);
        float4 ex4; ex4.x = e0; ex4.y = e1; ex4.z = e2; ex4.w = e3;
        *(float4*)&exv[wv][lane * 4] = ex4;
        srcs[wv][lane] = src;
        lds_fence();
        for (int k = g; k < deg; k += 4) {
            float4 ex = *(const float4*)&exv[wv][k * 4];
            int s2_ = srcs[wv][k];
            ushort4 u = *(const ushort4*)(H0b + (size_t)(tb + s2_) * 64 + il * 4);
            floatx4 xv = { bfu(u.x), bfu(u.y), bfu(u.z), bfu(u.w) };
            acc4[0] += ex.x * xv;
            acc4[1] += ex.y * xv;
            acc4[2] += ex.z * xv;
            acc4[3] += ex.w * xv;
        }
        if (do_out && valid) {
            int eid = csr_eid[e];
            float4 o4; o4.x = e0 * i0; o4.y = e1 * i1; o4.z = e2 * i2; o4.w = e3 * i3;
            *(float4*)(out_alpha + (size_t)eid * 4) = o4;
        }
    } else {
        float s0 = 0.f, s1 = 0.f, s2 = 0.f, s3 = 0.f;
        for (int e = rs + lane; e < re; e += 64) {
            int src = csr_src[e];
            float4 as = *(const float4*)(ALS1 + (size_t)(tb + src) * 4);
            float l0 = as.x + ad.x; l0 = l0 > 0.f ? l0 : 0.2f * l0; s0 += __expf(fminf(l0, 80.f));
            float l1 = as.y + ad.y; l1 = l1 > 0.f ? l1 : 0.2f * l1; s1 += __expf(fminf(l1, 80.f));
            float l2 = as.z + ad.z; l2 = l2 > 0.f ? l2 : 0.2f * l2; s2 += __expf(fminf(l2, 80.f));
            float l3 = as.w + ad.w; l3 = l3 > 0.f ? l3 : 0.2f * l3; s3 += __expf(fminf(l3, 80.f));
        }
#pragma unroll
        for (int o = 32; o; o >>= 1) {
            s0 += __shfl_xor(s0, o, 64); s1 += __shfl_xor(s1, o, 64);
            s2 += __shfl_xor(s2, o, 64); s3 += __shfl_xor(s3, o, 64);
        }
        float j0 = 1.f / (s0 + 1e-16f), j1 = 1.f / (s1 + 1e-16f);
        float j2 = 1.f / (s2 + 1e-16f), j3 = 1.f / (s3 + 1e-16f);
        for (int e0_ = rs; e0_ < re; e0_ += 4) {
            int e = e0_ + g;
            if (e < re) {
                int src = csr_src[e];
                float4 as = *(const float4*)(ALS1 + (size_t)(tb + src) * 4);
                float l0 = as.x + ad.x; l0 = l0 > 0.f ? l0 : 0.2f * l0;
                float l1 = as.y + ad.y; l1 = l1 > 0.f ? l1 : 0.2f * l1;
                float l2 = as.z + ad.z; l2 = l2 > 0.f ? l2 : 0.2f * l2;
                float l3 = as.w + ad.w; l3 = l3 > 0.f ? l3 : 0.2f * l3;
                float al0 = __expf(fminf(l0, 80.f)) * j0;
                float al1 = __expf(fminf(l1, 80.f)) * j1;
                float al2 = __expf(fminf(l2, 80.f)) * j2;
                float al3 = __expf(fminf(l3, 80.f)) * j3;
                if (do_out && il == 0) {
                    int eid = csr_eid[e];
                    float4 o4; o4.x = al0; o4.y = al1; o4.z = al2; o4.w = al3;
                    *(float4*)(out_alpha + (size_t)eid * 4) = o4;
                }
                ushort4 u = *(const ushort4*)(H0b + (size_t)(tb + src) * 64 + il * 4);
                floatx4 xv = { bfu(u.x), bfu(u.y), bfu(u.z), bfu(u.w) };
                acc4[0] += al0 * xv;
                acc4[1] += al1 * xv;
                acc4[2] += al2 * xv;
                acc4[3] += al3 * xv;
            }
        }
        i0 = i1 = i2 = i3 = 1.f;
    }
    acc4[0] *= i0; acc4[1] *= i1; acc4[2] *= i2; acc4[3] *= i3;
#pragma unroll
    for (int o = 16; o <= 32; o <<= 1)
#pragma unroll
        for (int hh = 0; hh < 4; hh++)
#pragma unroll
            for (int j = 0; j < 4; j++)
                acc4[hh][j] += __shfl_xor(acc4[hh][j], o, 64);
    if (g == 0) {
        int cb = il * 4;
        size_t ob = (size_t)wid * 256 + cb;
#pragma unroll
        for (int hh = 0; hh < 4; hh++) {
            ushort4 o4;
            o4.x = f2bu(acc4[hh][0]); o4.y = f2bu(acc4[hh][1]);
            o4.z = f2bu(acc4[hh][2]); o4.w = f2bu(acc4[hh][3]);
            *(ushort4*)(AGG1b + ob + hh * 64) = o4;
        }
    }
}

/* ---------------- epilogue GEMM (MFMA): AGG @ Wbig + LN -----------------
   B-frags read directly from pre-transposed global W1tb (32 KB, L2-hot);
   zero LDS, no barrier. */
__global__ __launch_bounds__(256) void k_post1(const bf16* __restrict__ AGG1b,
                                               const bf16* __restrict__ W1tb,
                                               const float* __restrict__ b1,
                                               const float* __restrict__ ln_g,
                                               const float* __restrict__ ln_b,
                                               bf16* __restrict__ HSb) {
    int tid = threadIdx.x;
    int wv = tid >> 6, lane = tid & 63;
    int tile = blockIdx.x * 4 + wv;
    if (tile >= NTILES) return;
    int rb = tile * 16;
    int m = lane & 15, quad = lane >> 4;
    const bf16* arow = AGG1b + (size_t)(rb + m) * 256 + quad * 8;
    short8 af[8];
#pragma unroll
    for (int kb = 0; kb < 8; kb++) af[kb] = *(const short8*)(arow + kb * 32);
    floatx4 acc[4];
#pragma unroll
    for (int ct = 0; ct < 4; ct++) {
        const bf16* wrow = W1tb + (ct * 16 + m) * 256 + quad * 8;
        floatx4 a = {0.f, 0.f, 0.f, 0.f};
#pragma unroll
        for (int kb = 0; kb < 8; kb++) {
            short8 bf = *(const short8*)(wrow + kb * 32);
            a = __builtin_amdgcn_mfma_f32_16x16x32_bf16(af[kb], bf, a, 0, 0, 0);
        }
        acc[ct] = a;
    }
    float b1v[4], ggv[4], bbv[4];
#pragma unroll
    for (int ct = 0; ct < 4; ct++) {
        b1v[ct] = b1[ct * 16 + m]; ggv[ct] = ln_g[ct * 16 + m]; bbv[ct] = ln_b[ct * 16 + m];
    }
#pragma unroll
    for (int r = 0; r < 4; r++) {
        float v[4];
        float s = 0.f;
#pragma unroll
        for (int ct = 0; ct < 4; ct++) {
            float t_ = acc[ct][r] * 0.25f + b1v[ct];
            t_ = t_ > 0.f ? t_ : (__expf(t_) - 1.f);
            v[ct] = t_; s += t_;
        }
#pragma unroll
        for (int o = 8; o; o >>= 1) s += __shfl_xor(s, o, 64);
        float mu = s * (1.f / 64.f);
        float q = 0.f;
#pragma unroll
        for (int ct = 0; ct < 4; ct++) { float d = v[ct] - mu; q += d * d; }
#pragma unroll
        for (int o = 8; o; o >>= 1) q += __shfl_xor(q, o, 64);
        float rinv = rsqrtf(q * (1.f / 64.f) + 1e-5f);
        int row = rb + quad * 4 + r;
#pragma unroll
        for (int ct = 0; ct < 4; ct++)
            HSb[(size_t)row * 64 + ct * 16 + m] =
                __float2bfloat16((v[ct] - mu) * rinv * ggv[ct] + bbv[ct]);
    }
}

/* ---------------- GRU: ALL steps fused in one MFMA kernel ---------------- */
__global__ __launch_bounds__(256) void k_gru(const bf16* __restrict__ HSb,
                                             const float* __restrict__ W_ih,
                                             const float* __restrict__ b_ih,
                                             const float* __restrict__ W_hh,
                                             const float* __restrict__ b_hh,
                                             float* __restrict__ outh) {
    __shared__ __align__(16) bf16 wi[192 * 64];        /* 24 KB, [j][k] */
    __shared__ __align__(16) bf16 wh[192 * 64];        /* 24 KB, [j][k] */
    __shared__ __align__(16) bf16 hbuf[4][16 * 72];    /* 9 KB, stride-72 pad */
    int tid = threadIdx.x;
    for (int i = tid; i < 12288; i += 256) {
        wi[i] = __float2bfloat16(W_ih[i]);
        wh[i] = __float2bfloat16(W_hh[i]);
    }
    __syncthreads();
    int wv = tid >> 6, lane = tid & 63;
    int tile = blockIdx.x * 4 + wv;
    if (tile >= N_NODES / 16) return;
    int rb = tile * 16;
    int m = lane & 15, quad = lane >> 4;
    bf16* hb = &hbuf[wv][0];
    float bi_[12], bh_[12];
#pragma unroll
    for (int ct = 0; ct < 12; ct++) { bi_[ct] = b_ih[ct * 16 + m]; bh_[ct] = b_hh[ct * 16 + m]; }
    float hprev[4][4];
#pragma unroll
    for (int ct = 0; ct < 4; ct++)
#pragma unroll
        for (int r = 0; r < 4; r++) hprev[ct][r] = 0.f;

    for (int t = 0; t < T_STEPS; t++) {
        const bf16* xr = HSb + ((size_t)t * N_NODES + rb + m) * 64;
        short8 ax0 = *(const short8*)(xr + quad * 8);
        short8 ax1 = *(const short8*)(xr + 32 + quad * 8);
        short8 ah0, ah1;
        if (t > 0) {
            ah0 = *(const short8*)(hb + m * 72 + quad * 8);
            ah1 = *(const short8*)(hb + m * 72 + 32 + quad * 8);
        }
        floatx4 rz[8];
        floatx4 gg_i[4];
        floatx4 gg_h[4];
#pragma unroll
        for (int ct = 0; ct < 8; ct++) {
            int cb = ct * 16;
            short8 b0 = *(const short8*)(wi + (cb + m) * 64 + quad * 8);
            short8 b1 = *(const short8*)(wi + (cb + m) * 64 + 32 + quad * 8);
            floatx4 a = {0.f, 0.f, 0.f, 0.f};
            a = __builtin_amdgcn_mfma_f32_16x16x32_bf16(ax0, b0, a, 0, 0, 0);
            a = __builtin_amdgcn_mfma_f32_16x16x32_bf16(ax1, b1, a, 0, 0, 0);
            if (t > 0) {
                short8 c0 = *(const short8*)(wh + (cb + m) * 64 + quad * 8);
                short8 c1 = *(const short8*)(wh + (cb + m) * 64 + 32 + quad * 8);
                a = __builtin_amdgcn_mfma_f32_16x16x32_bf16(ah0, c0, a, 0, 0, 0);
                a = __builtin_amdgcn_mfma_f32_16x16x32_bf16(ah1, c1, a, 0, 0, 0);
            }
            rz[ct] = a;
        }
#pragma unroll
        for (int ct = 0; ct < 4; ct++) {
            int cb = (ct + 8) * 16;
            short8 b0 = *(const short8*)(wi + (cb + m) * 64 + quad * 8);
            short8 b1 = *(const short8*)(wi + (cb + m) * 64 + 32 + quad * 8);
            floatx4 a = {0.f, 0.f, 0.f, 0.f};
            a = __builtin_amdgcn_mfma_f32_16x16x32_bf16(ax0, b0, a, 0, 0, 0);
            a = __builtin_amdgcn_mfma_f32_16x16x32_bf16(ax1, b1, a, 0, 0, 0);
            gg_i[ct] = a;
            floatx4 c = {0.f, 0.f, 0.f, 0.f};
            if (t > 0) {
                short8 c0 = *(const short8*)(wh + (cb + m) * 64 + quad * 8);
                short8 c1 = *(const short8*)(wh + (cb + m) * 64 + 32 + quad * 8);
                c = __builtin_amdgcn_mfma_f32_16x16x32_bf16(ah0, c0, c, 0, 0, 0);
                c = __builtin_amdgcn_mfma_f32_16x16x32_bf16(ah1, c1, c, 0, 0, 0);
            }
            gg_h[ct] = c;
        }
#pragma unroll
        for (int ct = 0; ct < 4; ct++) {
#pragma unroll
            for (int r = 0; r < 4; r++) {
                float rr = 1.f / (1.f + __expf(-(rz[ct][r] + bi_[ct] + bh_[ct])));
                float z  = 1.f / (1.f + __expf(-(rz[ct + 4][r] + bi_[ct + 4] + bh_[ct + 4])));
                float g  = tanhf(gg_i[ct][r] + bi_[ct + 8] + rr * (gg_h[ct][r] + bh_[ct + 8]));
                hprev[ct][r] = (1.f - z) * g + z * hprev[ct][r];
            }
        }
        if (t < T_STEPS - 1) {
#pragma unroll
            for (int ct = 0; ct < 4; ct++)
#pragma unroll
                for (int r = 0; r < 4; r++)
                    hb[(quad * 4 + r) * 72 + ct * 16 + m] = __float2bfloat16(hprev[ct][r]);
            lds_fence();
        }
    }
#pragma unroll
    for (int ct = 0; ct < 4; ct++)
#pragma unroll
        for (int r = 0; r < 4; r++)
            outh[(size_t)(rb + quad * 4 + r) * 64 + ct * 16 + m] = hprev[ct][r];
}

/* ---------------- output writer (fp32) ---------------- */

__global__ void k_out_ei(const int* __restrict__ ei, float* __restrict__ out) {
    int i = blockIdx.x * blockDim.x + threadIdx.x;
    if (i >= 2 * EP) return;
    int v;
    if (i < EP) {
        v = (i < E_EDGES) ? ei[i] : (i - E_EDGES);                 // src row
    } else {
        int jj = i - EP;
        v = (jj < E_EDGES) ? ei[E_EDGES + jj] : (jj - E_EDGES);    // dst row
    }
    out[i] = (float)v;
}

/* ---------------- launch ---------------- */

extern "C" void kernel_launch(void* const* d_in, const int* in_sizes, int n_in,
                              void* d_out, int out_size, void* d_ws, size_t ws_size,
                              hipStream_t stream) {
    const float* x      = (const float*)d_in[0];
    const int*   ei     = (const int*)d_in[1];
    const float* W0     = (const float*)d_in[2];
    const float* a_src0 = (const float*)d_in[3];
    const float* a_dst0 = (const float*)d_in[4];
    const float* b0     = (const float*)d_in[5];
    const float* W1     = (const float*)d_in[6];
    const float* a_src1 = (const float*)d_in[7];
    const float* a_dst1 = (const float*)d_in[8];
    const float* b1     = (const float*)d_in[9];
    const float* ln_g   = (const float*)d_in[10];
    const float* ln_b   = (const float*)d_in[11];
    const float* W_ih   = (const float*)d_in[12];
    const float* W_hh   = (const float*)d_in[13];
    const float* b_ih   = (const float*)d_in[14];
    const float* b_hh   = (const float*)d_in[15];
    float* out = (float*)d_out;

    char* w = (char*)d_ws;
    size_t off = 0;
    auto take = [&](size_t bytes) -> void* {
        void* p = w + off;
        off = (off + bytes + 255) & ~(size_t)255;
        return p;
    };
    int*   counts  = (int*)take(N_NODES * 4);
    int*   fill    = (int*)take(N_NODES * 4);
    int*   rowst   = (int*)take((N_NODES + 1) * 4);
    int*   csr_src = (int*)take((size_t)EP * 4);
    int*   csr_eid = (int*)take((size_t)EP * 4);
    bf16*  XW0b    = (bf16*)take((size_t)TN * 64 * 2);
    float* ALS0    = (float*)take((size_t)TN * 4 * 4);
    float* ALD0    = (float*)take((size_t)TN * 4 * 4);
    bf16*  H0b     = (bf16*)take((size_t)TN * 64 * 2);
    float* P1s     = (float*)take(256 * 4);
    float* P1d     = (float*)take(256 * 4);
    bf16*  W1tb    = (bf16*)take(64 * 256 * 2);
    float* ALS1    = (float*)take((size_t)TN * 4 * 4);
    float* ALD1    = (float*)take((size_t)TN * 4 * 4);
    bf16*  AGG1b   = (bf16*)take((size_t)TN * 256 * 2);
    bf16*  HSb     = (bf16*)take((size_t)TN * 64 * 2);
    (void)ws_size; (void)in_sizes; (void)n_in; (void)out_size;

    const int B = 256;
    /* CSR build + prep */
    hipMemsetAsync(counts, 0, N_NODES * 4, stream);
    hipMemsetAsync(fill, 0, N_NODES * 4, stream);
    k_count<<<(EP + B - 1) / B, B, 0, stream>>>(ei, counts);
    k_scan<<<1, 1024, 0, stream>>>(counts, rowst);
    k_scatter<<<(EP + B - 1) / B, B, 0, stream>>>(ei, rowst, fill, csr_src, csr_eid);
    k_prep1<<<1, B, 0, stream>>>(W1, a_src1, a_dst1, P1s, P1d, W1tb);

    const int GT = (NTILES + 3) / 4;   /* 938 blocks for 16-row-tile MFMA kernels */
    /* GAT layer 0 */
    k_gemm0<<<GT, B, 0, stream>>>(x, W0, a_src0, a_dst0, XW0b, ALS0, ALD0);
    k_fused0<<<TN / 4, B, 0, stream>>>(rowst, csr_src, XW0b, ALS0, ALD0, b0, H0b);
    k_logits1<<<GT, B, 0, stream>>>(H0b, P1s, P1d, ALS1, ALD1);

    /* GAT layer 1 */
    k_fused1<<<TN / 4, B, 0, stream>>>(rowst, csr_src, csr_eid, H0b, ALS1, ALD1,
                                       AGG1b, out + (size_t)N_NODES * HID);
    k_post1<<<GT, B, 0, stream>>>(AGG1b, W1tb, b1, ln_g, ln_b, HSb);

    /* GRU: one fused kernel, all 6 steps, writes hT to out */
    k_gru<<<(N_NODES / 16 + 3) / 4, B, 0, stream>>>(HSb, W_ih, b_ih, W_hh, b_hh, out);

    /* edge-index output */
    k_out_ei<<<(2 * EP + B - 1) / B, B, 0, stream>>>(ei, out + (size_t)N_NODES * HID + (size_t)EP * HEADS);
}